// Round 14
// baseline (1393.639 us; speedup 1.0000x reference)
//
#include <hip/hip_runtime.h>
#include <math.h>

#define B 128
#define S 2048
#define V 800
#define E 128
#define H 64
#define NL 3
#define M (B*S)

typedef unsigned short ushort_t;
typedef float f32x2 __attribute__((ext_vector_type(2)));

__device__ __forceinline__ float bf2f(unsigned short u){
  return __uint_as_float(((unsigned int)u) << 16);
}
__device__ __forceinline__ unsigned short f2bf(float f){
  unsigned int u = __float_as_uint(f);
  u += 0x7fff + ((u >> 16) & 1);          // round-to-nearest-even
  return (unsigned short)(u >> 16);
}
// single-instr bf16 round (RNE) for the y-store (T12-verbatim mnemonic)
__device__ __forceinline__ unsigned short f2bf_fast(float f){
  unsigned r;
  asm("v_cvt_pk_bf16_f32 %0, %1, %1" : "=v"(r) : "v"(f));
  return (unsigned short)r;
}
__device__ __forceinline__ float fast_tanh(float x){
  float e = exp2f(2.885390082f * x);      // = exp(2x), one mul fewer
  return 1.f - 2.f*__builtin_amdgcn_rcpf(e+1.f);
}
__device__ __forceinline__ int clamp_t(int t){
  return t < 0 ? 0 : (t > S-1 ? S-1 : t);
}
// packed dual-f32 FMA, src1 LOW word broadcast to both halves via op_sel:
// lo += a.lo*b.lo ; hi += a.hi*b.lo  -> no {hv,hv} duplication movs needed.
__device__ __forceinline__ void pk_fma_b(f32x2& acc, f32x2 a, f32x2 b){
  asm("v_pk_fma_f32 %0, %1, %2, %0 op_sel:[0,0,0] op_sel_hi:[1,0,1]"
      : "+v"(acc) : "v"(a), "v"(b));
}

// ---- all-VALU 8x8 butterfly matvec (R11/R13-proven), op_sel dot (R14) -----
// Lane l owns h[l]. Rows per lane: l ^ G(k), G(k) = (k&3)|((k&4)<<2).
// Cols: preserve bits{0,1,4}; spread bits{2,3} (rot4 orbit) + bit5
// (permlane32 pair). Folds xor1/xor2 (quad_perm DPP) + xor16 (permlane16
// pair). Runtime calibration absorbs permlane pairing conventions.
// R14: gather ops write straight into the LOW half of persistent f32x2
// pairs (hi halves parked at 0, never read — op_sel broadcasts the low),
// removing the 16 v_mov/step pair-duplication of R13.
#define DPP_XOR1 0xB1    // quad_perm [1,0,3,2]
#define DPP_XOR2 0x4E    // quad_perm [2,3,0,1]
#define DPP_ROR4  0x124  // row_ror:4
#define DPP_ROR8  0x128  // row_ror:8
#define DPP_ROR12 0x12C  // row_ror:12
#define DPPI(v, ctrl) __builtin_amdgcn_update_dpp(0, (v), (ctrl), 0xf, 0xf, false)
#define DPPF(v, ctrl) __int_as_float(DPPI(__float_as_int(v), (ctrl)))
__device__ __forceinline__ float bperm(int addr, float v){
  return __int_as_float(__builtin_amdgcn_ds_bpermute(addr, __float_as_int(v)));
}
__device__ __host__ __forceinline__ constexpr int Gmask(int k){
  return (k & 3) | ((k & 4) << 2);      // {0,1,2,3,16,17,18,19}
}

#if __has_builtin(__builtin_amdgcn_permlane32_swap)
#define HAVE_PL32 1
#else
#define HAVE_PL32 0
#endif
#if __has_builtin(__builtin_amdgcn_permlane16_swap)
#define HAVE_PL16 1
#else
#define HAVE_PL16 0
#endif

#if HAVE_PL32
#define XOR32F(x) ({ auto r_ = __builtin_amdgcn_permlane32_swap(__float_as_uint(x), __float_as_uint(x), false, false); \
                     __uint_as_float(pick32 ? r_[0] : r_[1]); })
#else
#define XOR32F(x) bperm(ba32, (x))
#endif
#if HAVE_PL16
#define XOR16F(x) ({ auto r_ = __builtin_amdgcn_permlane16_swap(__float_as_uint(x), __float_as_uint(x), false, false); \
                     __uint_as_float(pick16 ? r_[0] : r_[1]); })
#else
#define XOR16F(x) bperm(ba16, (x))
#endif

// Calibration: fills pick16, pick32, cm[8] (true source lane of gather op j).
#define CALIB() do {                                                         \
  int mk_ = i;                                                               \
  int g32m_;                                                                 \
  if (HAVE_PL32) {                                                           \
    auto r_ = __builtin_amdgcn_permlane32_swap((unsigned)mk_, (unsigned)mk_, false, false); \
    pick32 = ((int)r_[0] == (mk_ ^ 32));                                     \
    g32m_ = pick32 ? (int)r_[0] : (int)r_[1];                                \
  } else {                                                                   \
    g32m_ = mk_ ^ 32;                                                        \
  }                                                                          \
  if (HAVE_PL16) {                                                           \
    auto r_ = __builtin_amdgcn_permlane16_swap((unsigned)mk_, (unsigned)mk_, false, false); \
    pick16 = ((int)r_[0] == (mk_ ^ 16));                                     \
  }                                                                          \
  cm[0]=mk_;   cm[1]=DPPI(mk_,DPP_ROR4);                                     \
  cm[2]=DPPI(mk_,DPP_ROR8);  cm[3]=DPPI(mk_,DPP_ROR12);                      \
  cm[4]=g32m_; cm[5]=DPPI(g32m_,DPP_ROR4);                                   \
  cm[6]=DPPI(g32m_,DPP_ROR8); cm[7]=DPPI(g32m_,DPP_ROR12);                   \
} while(0)

// W-tile load: wp[q*8+j] = (W[i^G(2q)][cm j], W[i^G(2q+1)][cm j])
#define LOAD_W8P(wbase) do {                                                 \
  _Pragma("unroll")                                                          \
  for (int q=0;q<4;++q){                                                     \
    const float* r0_ = (wbase) + (size_t)(i ^ Gmask(2*q))*H;                 \
    const float* r1_ = (wbase) + (size_t)(i ^ Gmask(2*q+1))*H;               \
    _Pragma("unroll")                                                        \
    for (int j=0;j<8;++j)                                                    \
      wp[q*8+j] = (f32x2){ r0_[cm[j]], r1_[cm[j]] };                         \
  }                                                                          \
} while(0)

// persistent broadcast pairs (hi halves parked at 0, never read)
#define DECL_HD() f32x2 hd0={0,0},hd1={0,0},hd2={0,0},hd3={0,0},             \
                        hd4={0,0},hd5={0,0},hd6={0,0},hd7={0,0}

// one recurrence step: gather writes pair-lows directly, 32 op_sel pk_fma
// tile dot (acc seeded in P0.x = row l), unpack, fold xor1,xor2 (DPP) +
// xor16 (permlane16 pair, calibrated pick), tanh. Updates h.
#define BSTEP(acc_expr)                                                      \
  {                                                                          \
    hd0.x = h;                                                               \
    hd1.x = DPPF(h, DPP_ROR4);                                               \
    hd2.x = DPPF(h, DPP_ROR8);                                               \
    hd3.x = DPPF(h, DPP_ROR12);                                              \
    hd4.x = XOR32F(h);                                                       \
    hd5.x = DPPF(hd4.x, DPP_ROR4);                                           \
    hd6.x = DPPF(hd4.x, DPP_ROR8);                                           \
    hd7.x = DPPF(hd4.x, DPP_ROR12);                                          \
    f32x2 P0_ = {(acc_expr), 0.f};                                           \
    f32x2 P1_ = {0.f, 0.f}, P2_ = {0.f, 0.f}, P3_ = {0.f, 0.f};              \
    pk_fma_b(P0_,wp[0],hd0); pk_fma_b(P1_,wp[8],hd0);                        \
    pk_fma_b(P2_,wp[16],hd0); pk_fma_b(P3_,wp[24],hd0);                      \
    pk_fma_b(P0_,wp[1],hd1); pk_fma_b(P1_,wp[9],hd1);                        \
    pk_fma_b(P2_,wp[17],hd1); pk_fma_b(P3_,wp[25],hd1);                      \
    pk_fma_b(P0_,wp[2],hd2); pk_fma_b(P1_,wp[10],hd2);                       \
    pk_fma_b(P2_,wp[18],hd2); pk_fma_b(P3_,wp[26],hd2);                      \
    pk_fma_b(P0_,wp[3],hd3); pk_fma_b(P1_,wp[11],hd3);                       \
    pk_fma_b(P2_,wp[19],hd3); pk_fma_b(P3_,wp[27],hd3);                      \
    pk_fma_b(P0_,wp[4],hd4); pk_fma_b(P1_,wp[12],hd4);                       \
    pk_fma_b(P2_,wp[20],hd4); pk_fma_b(P3_,wp[28],hd4);                      \
    pk_fma_b(P0_,wp[5],hd5); pk_fma_b(P1_,wp[13],hd5);                       \
    pk_fma_b(P2_,wp[21],hd5); pk_fma_b(P3_,wp[29],hd5);                      \
    pk_fma_b(P0_,wp[6],hd6); pk_fma_b(P1_,wp[14],hd6);                       \
    pk_fma_b(P2_,wp[22],hd6); pk_fma_b(P3_,wp[30],hd6);                      \
    pk_fma_b(P0_,wp[7],hd7); pk_fma_b(P1_,wp[15],hd7);                       \
    pk_fma_b(P2_,wp[23],hd7); pk_fma_b(P3_,wp[31],hd7);                      \
    float p0_=P0_.x, p1_=P0_.y, p2_=P1_.x, p3_=P1_.y;                        \
    float p4_=P2_.x, p5_=P2_.y, p6_=P3_.x, p7_=P3_.y;                        \
    p0_ += DPPF(p1_, DPP_XOR1); p2_ += DPPF(p3_, DPP_XOR1);                  \
    p4_ += DPPF(p5_, DPP_XOR1); p6_ += DPPF(p7_, DPP_XOR1);                  \
    p0_ += DPPF(p2_, DPP_XOR2); p4_ += DPPF(p6_, DPP_XOR2);                  \
    p0_ += XOR16F(p4_);                                                      \
    h = fast_tanh(p0_);                                                      \
  }
// ---------------------------------------------------------------------------

// pre_emb[v][n] = emb[v]·w_ih[0,n,:] + b_ih[0,n] + b_hh[0,n],  n = d*64+i
__global__ __launch_bounds__(128) void k_pre_emb(const float* __restrict__ emb,
    const float* __restrict__ w_ih, const float* __restrict__ b_ih, const float* __restrict__ b_hh,
    float* __restrict__ pe)
{
  const int v = blockIdx.x;
  const int n = threadIdx.x;           // 0..127
  const float* er = emb + (size_t)v*E;
  const float* wr = w_ih + (size_t)n*E;   // layer 0 rows
  float acc = b_ih[n] + b_hh[n];
  #pragma unroll
  for (int e=0;e<E;e+=4){
    float4 ev = *(const float4*)(er+e);
    float4 wv = *(const float4*)(wr+e);
    acc = fmaf(ev.x, wv.x, acc);
    acc = fmaf(ev.y, wv.y, acc);
    acc = fmaf(ev.z, wv.z, acc);
    acc = fmaf(ev.w, wv.w, acc);
  }
  pe[(size_t)v*128 + n] = acc;
}

// partial mean/max pools over S-chunks
__global__ __launch_bounds__(128) void k_pool(const int* __restrict__ x, const float* __restrict__ emb,
      float* __restrict__ psum, float* __restrict__ pmax)
{
  const int b = blockIdx.x, c = blockIdx.y, e = threadIdx.x;
  const int* xb = x + (size_t)b*S + c*(S/16);
  float s=0.f, m=-INFINITY;
  for (int k=0;k<S/16;++k){
    int v = xb[k];
    float val = emb[(size_t)v*E + e];
    s += val; m = fmaxf(m,val);
  }
  psum[((size_t)b*16 + c)*E + e] = s;
  pmax[((size_t)b*16 + c)*E + e] = m;
}

// layer-0 recurrence, fused gather: pre[t] = pe[x[t]] (pe is 409 KB -> L2-hot).
// One wave per (d,b) chain; all-VALU butterfly dot with op_sel pk_fma.
__global__ __attribute__((amdgpu_flat_work_group_size(64,64)))
__attribute__((amdgpu_waves_per_eu(1,1)))
void k_rec0(const int* __restrict__ x,
            const float* __restrict__ pe,
            ushort_t* __restrict__ y,
            const float* __restrict__ w_hh,
            float* __restrict__ hfin)
{
  const int c = blockIdx.x;           // 0..255
  const int d = c >> 7;
  const int b = c & 127;
  const int i = threadIdx.x;          // 0..63
  bool pick16=false, pick32=false;
  int cm[8];
  const int ba32 = (i^32)<<2, ba16 = (i^16)<<2;
  (void)ba32; (void)ba16;
  CALIB();
  f32x2 wp[32];
  LOAD_W8P(w_hh + (size_t)d*H*H);     // layer 0
  DECL_HD();
  const int* xb = x + (size_t)b*S;
  const float* peb = pe + d*H + i;    // + v*128 per step
  ushort_t* yb = y + (size_t)b*S*(2*H) + d*H + i;
  const int fwd = (d==0);
  const int dt = fwd ? 1 : -1;
  int t = fwd ? 0 : S-1;

  int vx[8];                          // x values for t .. t+7
  #pragma unroll
  for (int k=0;k<8;++k) vx[k] = xb[clamp_t(t + k*dt)];
  float pl[4];                        // pe rows for t .. t+3
  #pragma unroll
  for (int k=0;k<4;++k) pl[k] = peb[(size_t)vx[k]*128];
  float h = 0.f;

#define STEP0(r) do {                                                        \
    float acc = pl[(r)&3];                                                   \
    pl[(r)&3] = peb[(size_t)vx[((r)+4)&7]*128];  /* row for t+4 */           \
    vx[(r)&7] = xb[clamp_t(t + 8*dt)];           /* x for t+8  */            \
    BSTEP(acc);                                                              \
    yb[(size_t)t*(2*H)] = f2bf_fast(h);                                      \
    t += dt;                                                                 \
  } while(0)

  for (int tq=0; tq<S; tq+=8){
    STEP0(0); STEP0(1); STEP0(2); STEP0(3);
    STEP0(4); STEP0(5); STEP0(6); STEP0(7);
  }
#undef STEP0
  hfin[((size_t)d*B + b)*H + i] = h;
}

// layers 1,2 recurrence: pre streamed from HBM (134 MB), depth-8 prefetch
// ring; all-VALU butterfly dot with op_sel pk_fma; compile-time layer/write_y.
template<int LAYER, int WRITEY>
__global__ __attribute__((amdgpu_flat_work_group_size(64,64)))
__attribute__((amdgpu_waves_per_eu(1,1)))
void k_rec(const float* __restrict__ pre,
           ushort_t* __restrict__ y,
           const float* __restrict__ w_hh,
           float* __restrict__ hfin)
{
  const int c = blockIdx.x;           // 0..255
  const int d = c >> 7;
  const int b = c & 127;
  const int i = threadIdx.x;          // 0..63
  bool pick16=false, pick32=false;
  int cm[8];
  const int ba32 = (i^32)<<2, ba16 = (i^16)<<2;
  (void)ba32; (void)ba16;
  CALIB();
  f32x2 wp[32];
  LOAD_W8P(w_hh + (size_t)(LAYER*2+d)*H*H);
  DECL_HD();
  const float* pb = pre + ((size_t)d*M + (size_t)b*S)*H + i;
  ushort_t* yb = y + (size_t)b*S*(2*H) + d*H + i;
  const int fwd = (d==0);
  const int dt = fwd ? 1 : -1;
  int t = fwd ? 0 : S-1;

  float pl[8];                        // pre values for t .. t+7
  #pragma unroll
  for (int k=0;k<8;++k) pl[k] = pb[(size_t)clamp_t(t + k*dt)*H];
  float h = 0.f;

#define STEPR(r) do {                                                        \
    float acc = pl[r];                                                       \
    pl[r] = pb[(size_t)clamp_t(t + 8*dt)*H];     /* value for t+8 */         \
    BSTEP(acc);                                                              \
    if (WRITEY) yb[(size_t)t*(2*H)] = f2bf_fast(h);                          \
    t += dt;                                                                 \
  } while(0)

  for (int tq=0; tq<S; tq+=8){
    STEPR(0); STEPR(1); STEPR(2); STEPR(3);
    STEPR(4); STEPR(5); STEPR(6); STEPR(7);
  }
#undef STEPR
  hfin[((size_t)d*B + b)*H + i] = h;
}

// layers 1,2 input projection: [M,128]@[128,128]^T. Yin is bf16, W is fp32.
#define KC 32
__global__ __launch_bounds__(256) void k_gemm(const ushort_t* __restrict__ Yin,
     const float* __restrict__ w_ih, const float* __restrict__ b_ih,
     const float* __restrict__ b_hh, float* __restrict__ pre, int layer)
{
  __shared__ float sY[KC][132];
  __shared__ float sW[KC][132];
  const int tid = threadIdx.x;
  const int m0 = blockIdx.x * 128;
  const int tn = (tid & 15) * 8;
  const int tm = (tid >> 4) * 8;
  float acc[8][8];
  #pragma unroll
  for (int a=0;a<8;++a)
    #pragma unroll
    for (int q=0;q<8;++q) acc[a][q]=0.f;
  const float* Wb = w_ih + (size_t)layer*2*H*E;
  for (int kc=0; kc<E; kc+=KC){
    #pragma unroll
    for (int r=0;r<2;++r){
      int idx = r*256 + tid;     // 0..511
      int ym = idx >> 2;         // 0..127
      int yk = (idx & 3)*8;      // 0,8,16,24
      const ushort_t* p = Yin + (size_t)(m0+ym)*E + kc + yk;
      ushort4 a = *(const ushort4*)p;
      ushort4 bq = *(const ushort4*)(p+4);
      sY[yk+0][ym]=bf2f(a.x);  sY[yk+1][ym]=bf2f(a.y);  sY[yk+2][ym]=bf2f(a.z);  sY[yk+3][ym]=bf2f(a.w);
      sY[yk+4][ym]=bf2f(bq.x); sY[yk+5][ym]=bf2f(bq.y); sY[yk+6][ym]=bf2f(bq.z); sY[yk+7][ym]=bf2f(bq.w);
    }
    #pragma unroll
    for (int r=0;r<4;++r){
      int idx = r*256 + tid;     // 0..1023
      int wn = idx >> 3;         // 0..127
      int wk = (idx & 7)*4;      // 0..28
      float4 v = *(const float4*)(Wb + (size_t)wn*E + kc + wk);
      sW[wk+0][wn]=v.x; sW[wk+1][wn]=v.y; sW[wk+2][wn]=v.z; sW[wk+3][wn]=v.w;
    }
    __syncthreads();
    #pragma unroll 4
    for (int k=0;k<KC;++k){
      float4 a0 = *(const float4*)&sY[k][tm];
      float4 a1 = *(const float4*)&sY[k][tm+4];
      float4 b0 = *(const float4*)&sW[k][tn];
      float4 b1 = *(const float4*)&sW[k][tn+4];
      float am[8]={a0.x,a0.y,a0.z,a0.w,a1.x,a1.y,a1.z,a1.w};
      float bn[8]={b0.x,b0.y,b0.z,b0.w,b1.x,b1.y,b1.z,b1.w};
      #pragma unroll
      for (int mi=0;mi<8;++mi)
        #pragma unroll
        for (int ni=0;ni<8;++ni)
          acc[mi][ni] = fmaf(am[mi], bn[ni], acc[mi][ni]);
    }
    __syncthreads();
  }
  const int d = tn >> 6;
  const int i0 = tn & 63;
  float bias[8];
  #pragma unroll
  for (int ni=0;ni<8;++ni)
    bias[ni] = b_ih[(size_t)(layer*2+d)*H + i0+ni] + b_hh[(size_t)(layer*2+d)*H + i0+ni];
  #pragma unroll
  for (int mi=0;mi<8;++mi){
    size_t off = ((size_t)d*M + (m0+tm+mi))*H + i0;
    float4 o0 = make_float4(acc[mi][0]+bias[0], acc[mi][1]+bias[1], acc[mi][2]+bias[2], acc[mi][3]+bias[3]);
    float4 o1 = make_float4(acc[mi][4]+bias[4], acc[mi][5]+bias[5], acc[mi][6]+bias[6], acc[mi][7]+bias[7]);
    *(float4*)(pre + off)     = o0;
    *(float4*)(pre + off + 4) = o1;
  }
}

// final FC head; also reduces the 16 pool partials. fp32 in/out.
__global__ __launch_bounds__(128) void k_fc(const float* __restrict__ psum, const float* __restrict__ pmax,
    const float* __restrict__ hfin, const float* __restrict__ fc1_w, const float* __restrict__ fc1_b,
    const float* __restrict__ fc2_w, const float* __restrict__ fc2_b, float* __restrict__ out)
{
  const int b = blockIdx.x, tid = threadIdx.x;
  __shared__ __align__(16) float comb[384];
  __shared__ float red[2];
  float s=0.f, m=-INFINITY;
  #pragma unroll
  for (int c=0;c<16;++c){
    s += psum[((size_t)b*16+c)*E + tid];
    m = fmaxf(m, pmax[((size_t)b*16+c)*E + tid]);
  }
  comb[128+tid] = s*(1.f/2048.f);
  comb[256+tid] = m;
  comb[tid] = (tid<64) ? hfin[(size_t)b*H + tid] : hfin[((size_t)B + b)*H + (tid-64)];
  __syncthreads();
  float acc = fc1_b[tid];
  const float4* wrow = (const float4*)(fc1_w + (size_t)tid*384);
  const float4* cb = (const float4*)comb;
  #pragma unroll 8
  for (int k=0;k<96;++k){
    float4 wv = wrow[k]; float4 cv = cb[k];
    acc = fmaf(wv.x,cv.x,acc); acc = fmaf(wv.y,cv.y,acc);
    acc = fmaf(wv.z,cv.z,acc); acc = fmaf(wv.w,cv.w,acc);
  }
  acc = fmaxf(acc, 0.f);
  float p = acc * fc2_w[tid];
  #pragma unroll
  for (int off=32; off>0; off>>=1) p += __shfl_down(p, off);
  if ((tid & 63)==0) red[tid>>6] = p;
  __syncthreads();
  if (tid==0) out[b] = red[0] + red[1] + fc2_b[0];
}

extern "C" void kernel_launch(void* const* d_in, const int* in_sizes, int n_in,
                              void* d_out, int out_size, void* d_ws, size_t ws_size,
                              hipStream_t stream)
{
  const int*   x     = (const int*)  d_in[0];
  const float* emb   = (const float*)d_in[1];
  const float* w_ih  = (const float*)d_in[2];
  const float* w_hh  = (const float*)d_in[3];
  const float* b_ih  = (const float*)d_in[4];
  const float* b_hh  = (const float*)d_in[5];
  const float* fc1_w = (const float*)d_in[6];
  const float* fc1_b = (const float*)d_in[7];
  const float* fc2_w = (const float*)d_in[8];
  const float* fc2_b = (const float*)d_in[9];
  float* out = (float*)d_out;

  // workspace: keep under ~204 MB
  char* ws = (char*)d_ws;
  float*    pre  = (float*)(ws);                                     // 2*M*H f32  = 134.2 MB (layers 1,2 only)
  ushort_t* y    = (ushort_t*)(ws + (size_t)2*M*H*4);                // M*128 bf16 =  67.1 MB
  float*    pe   = (float*)(ws + (size_t)2*M*H*4 + (size_t)M*128*2); // V*128 f32
  float*    psum = pe   + (size_t)V*128;                             // B*16*E f32
  float*    pmax = psum + (size_t)B*16*E;                            // B*16*E f32
  float*    hfin = pmax + (size_t)B*16*E;                            // 2*B*H f32

  k_pre_emb<<<V, 128, 0, stream>>>(emb, w_ih, b_ih, b_hh, pe);
  k_pool<<<dim3(B,16), 128, 0, stream>>>(x, emb, psum, pmax);
  k_rec0<<<256, 64, 0, stream>>>(x, pe, y, w_hh, hfin);
  k_gemm<<<M/128, 256, 0, stream>>>(y, w_ih, b_ih, b_hh, pre, 1);
  k_rec<1,1><<<256, 64, 0, stream>>>(pre, y, w_hh, hfin);
  k_gemm<<<M/128, 256, 0, stream>>>(y, w_ih, b_ih, b_hh, pre, 2);
  k_rec<2,0><<<256, 64, 0, stream>>>(pre, y, w_hh, hfin);
  k_fc<<<B, 128, 0, stream>>>(psum, pmax, hfin, fc1_w, fc1_b, fc2_w, fc2_b, out);
}

// Round 15
// 1324.534 us; speedup vs baseline: 1.0522x; 1.0522x over previous
//
#include <hip/hip_runtime.h>
#include <math.h>

#define B 128
#define S 2048
#define V 800
#define E 128
#define H 64
#define NL 3
#define M (B*S)

typedef unsigned short ushort_t;
typedef float f32x2 __attribute__((ext_vector_type(2)));

__device__ __forceinline__ float bf2f(unsigned short u){
  return __uint_as_float(((unsigned int)u) << 16);
}
__device__ __forceinline__ unsigned short f2bf(float f){
  unsigned int u = __float_as_uint(f);
  u += 0x7fff + ((u >> 16) & 1);          // round-to-nearest-even
  return (unsigned short)(u >> 16);
}
// single-instr bf16 round (RNE) for the y-store
__device__ __forceinline__ unsigned short f2bf_fast(float f){
  unsigned r;
  asm("v_cvt_pk_bf16_f32 %0, %1, %1" : "=v"(r) : "v"(f));
  return (unsigned short)r;
}
#if __has_builtin(__builtin_amdgcn_exp2f)
#define EXP2F(x) __builtin_amdgcn_exp2f(x)
#else
#define EXP2F(x) exp2f(x)
#endif
__device__ __forceinline__ float fast_tanh(float x){
  float e = EXP2F(2.885390082f * x);      // = exp(2x); raw v_exp_f32
  return 1.f - 2.f*__builtin_amdgcn_rcpf(e+1.f);
}
// packed dual-f32 FMA, src1 LOW word broadcast to both halves via op_sel
__device__ __forceinline__ void pk_fma_b(f32x2& acc, f32x2 a, f32x2 b){
  asm("v_pk_fma_f32 %0, %1, %2, %0 op_sel:[0,0,0] op_sel_hi:[1,0,1]"
      : "+v"(acc) : "v"(a), "v"(b));
}

// ---- all-VALU 8x8 butterfly matvec (R11/R13-proven) -----------------------
// Lane l owns h[l]. Rows per lane: l ^ G(k), G(k) = (k&3)|((k&4)<<2).
// Cols: preserve bits{0,1,4}; spread bits{2,3} (rot4 orbit) + bit5
// (permlane32 pair). Folds xor1/xor2 (quad_perm DPP) + xor16 (permlane16
// pair). Runtime calibration absorbs permlane pairing conventions.
// R15: strength-reduced addressing (pointer increments, no 64-bit muls or
// clamps in the 2040-step main loop; 8-step tail uses ring-resident data).
#define DPP_XOR1 0xB1    // quad_perm [1,0,3,2]
#define DPP_XOR2 0x4E    // quad_perm [2,3,0,1]
#define DPP_ROR4  0x124  // row_ror:4
#define DPP_ROR8  0x128  // row_ror:8
#define DPP_ROR12 0x12C  // row_ror:12
#define DPPI(v, ctrl) __builtin_amdgcn_update_dpp(0, (v), (ctrl), 0xf, 0xf, false)
#define DPPF(v, ctrl) __int_as_float(DPPI(__float_as_int(v), (ctrl)))
__device__ __forceinline__ float bperm(int addr, float v){
  return __int_as_float(__builtin_amdgcn_ds_bpermute(addr, __float_as_int(v)));
}
__device__ __host__ __forceinline__ constexpr int Gmask(int k){
  return (k & 3) | ((k & 4) << 2);      // {0,1,2,3,16,17,18,19}
}

#if __has_builtin(__builtin_amdgcn_permlane32_swap)
#define HAVE_PL32 1
#else
#define HAVE_PL32 0
#endif
#if __has_builtin(__builtin_amdgcn_permlane16_swap)
#define HAVE_PL16 1
#else
#define HAVE_PL16 0
#endif

#if HAVE_PL32
#define XOR32F(x) ({ auto r_ = __builtin_amdgcn_permlane32_swap(__float_as_uint(x), __float_as_uint(x), false, false); \
                     __uint_as_float(pick32 ? r_[0] : r_[1]); })
#else
#define XOR32F(x) bperm(ba32, (x))
#endif
#if HAVE_PL16
#define XOR16F(x) ({ auto r_ = __builtin_amdgcn_permlane16_swap(__float_as_uint(x), __float_as_uint(x), false, false); \
                     __uint_as_float(pick16 ? r_[0] : r_[1]); })
#else
#define XOR16F(x) bperm(ba16, (x))
#endif

// Calibration: fills pick16, pick32, cm[8] (true source lane of gather op j).
#define CALIB() do {                                                         \
  int mk_ = i;                                                               \
  int g32m_;                                                                 \
  if (HAVE_PL32) {                                                           \
    auto r_ = __builtin_amdgcn_permlane32_swap((unsigned)mk_, (unsigned)mk_, false, false); \
    pick32 = ((int)r_[0] == (mk_ ^ 32));                                     \
    g32m_ = pick32 ? (int)r_[0] : (int)r_[1];                                \
  } else {                                                                   \
    g32m_ = mk_ ^ 32;                                                        \
  }                                                                          \
  if (HAVE_PL16) {                                                           \
    auto r_ = __builtin_amdgcn_permlane16_swap((unsigned)mk_, (unsigned)mk_, false, false); \
    pick16 = ((int)r_[0] == (mk_ ^ 16));                                     \
  }                                                                          \
  cm[0]=mk_;   cm[1]=DPPI(mk_,DPP_ROR4);                                     \
  cm[2]=DPPI(mk_,DPP_ROR8);  cm[3]=DPPI(mk_,DPP_ROR12);                      \
  cm[4]=g32m_; cm[5]=DPPI(g32m_,DPP_ROR4);                                   \
  cm[6]=DPPI(g32m_,DPP_ROR8); cm[7]=DPPI(g32m_,DPP_ROR12);                   \
} while(0)

// W-tile load: wp[q*8+j] = (W[i^G(2q)][cm j], W[i^G(2q+1)][cm j])
#define LOAD_W8P(wbase) do {                                                 \
  _Pragma("unroll")                                                          \
  for (int q=0;q<4;++q){                                                     \
    const float* r0_ = (wbase) + (size_t)(i ^ Gmask(2*q))*H;                 \
    const float* r1_ = (wbase) + (size_t)(i ^ Gmask(2*q+1))*H;               \
    _Pragma("unroll")                                                        \
    for (int j=0;j<8;++j)                                                    \
      wp[q*8+j] = (f32x2){ r0_[cm[j]], r1_[cm[j]] };                         \
  }                                                                          \
} while(0)

// persistent broadcast pairs (hi halves parked at 0, never read)
#define DECL_HD() f32x2 hd0={0,0},hd1={0,0},hd2={0,0},hd3={0,0},             \
                        hd4={0,0},hd5={0,0},hd6={0,0},hd7={0,0}

// one recurrence step: gather, 32 op_sel pk_fma tile dot (acc seeded in
// P0.x = row l), unpack, fold xor1,xor2 (DPP) + xor16, tanh. Updates h.
#define BSTEP(acc_expr)                                                      \
  {                                                                          \
    hd0.x = h;                                                               \
    hd1.x = DPPF(h, DPP_ROR4);                                               \
    hd2.x = DPPF(h, DPP_ROR8);                                               \
    hd3.x = DPPF(h, DPP_ROR12);                                              \
    hd4.x = XOR32F(h);                                                       \
    hd5.x = DPPF(hd4.x, DPP_ROR4);                                           \
    hd6.x = DPPF(hd4.x, DPP_ROR8);                                           \
    hd7.x = DPPF(hd4.x, DPP_ROR12);                                          \
    f32x2 P0_ = {(acc_expr), 0.f};                                           \
    f32x2 P1_ = {0.f, 0.f}, P2_ = {0.f, 0.f}, P3_ = {0.f, 0.f};              \
    pk_fma_b(P0_,wp[0],hd0); pk_fma_b(P1_,wp[8],hd0);                        \
    pk_fma_b(P2_,wp[16],hd0); pk_fma_b(P3_,wp[24],hd0);                      \
    pk_fma_b(P0_,wp[1],hd1); pk_fma_b(P1_,wp[9],hd1);                        \
    pk_fma_b(P2_,wp[17],hd1); pk_fma_b(P3_,wp[25],hd1);                      \
    pk_fma_b(P0_,wp[2],hd2); pk_fma_b(P1_,wp[10],hd2);                       \
    pk_fma_b(P2_,wp[18],hd2); pk_fma_b(P3_,wp[26],hd2);                      \
    pk_fma_b(P0_,wp[3],hd3); pk_fma_b(P1_,wp[11],hd3);                       \
    pk_fma_b(P2_,wp[19],hd3); pk_fma_b(P3_,wp[27],hd3);                      \
    pk_fma_b(P0_,wp[4],hd4); pk_fma_b(P1_,wp[12],hd4);                       \
    pk_fma_b(P2_,wp[20],hd4); pk_fma_b(P3_,wp[28],hd4);                      \
    pk_fma_b(P0_,wp[5],hd5); pk_fma_b(P1_,wp[13],hd5);                       \
    pk_fma_b(P2_,wp[21],hd5); pk_fma_b(P3_,wp[29],hd5);                      \
    pk_fma_b(P0_,wp[6],hd6); pk_fma_b(P1_,wp[14],hd6);                       \
    pk_fma_b(P2_,wp[22],hd6); pk_fma_b(P3_,wp[30],hd6);                      \
    pk_fma_b(P0_,wp[7],hd7); pk_fma_b(P1_,wp[15],hd7);                       \
    pk_fma_b(P2_,wp[23],hd7); pk_fma_b(P3_,wp[31],hd7);                      \
    float p0_=P0_.x, p1_=P0_.y, p2_=P1_.x, p3_=P1_.y;                        \
    float p4_=P2_.x, p5_=P2_.y, p6_=P3_.x, p7_=P3_.y;                        \
    p0_ += DPPF(p1_, DPP_XOR1); p2_ += DPPF(p3_, DPP_XOR1);                  \
    p4_ += DPPF(p5_, DPP_XOR1); p6_ += DPPF(p7_, DPP_XOR1);                  \
    p0_ += DPPF(p2_, DPP_XOR2); p4_ += DPPF(p6_, DPP_XOR2);                  \
    p0_ += XOR16F(p4_);                                                      \
    h = fast_tanh(p0_);                                                      \
  }
// ---------------------------------------------------------------------------

// pre_emb[v][n] = emb[v]·w_ih[0,n,:] + b_ih[0,n] + b_hh[0,n],  n = d*64+i
__global__ __launch_bounds__(128) void k_pre_emb(const float* __restrict__ emb,
    const float* __restrict__ w_ih, const float* __restrict__ b_ih, const float* __restrict__ b_hh,
    float* __restrict__ pe)
{
  const int v = blockIdx.x;
  const int n = threadIdx.x;           // 0..127
  const float* er = emb + (size_t)v*E;
  const float* wr = w_ih + (size_t)n*E;   // layer 0 rows
  float acc = b_ih[n] + b_hh[n];
  #pragma unroll
  for (int e=0;e<E;e+=4){
    float4 ev = *(const float4*)(er+e);
    float4 wv = *(const float4*)(wr+e);
    acc = fmaf(ev.x, wv.x, acc);
    acc = fmaf(ev.y, wv.y, acc);
    acc = fmaf(ev.z, wv.z, acc);
    acc = fmaf(ev.w, wv.w, acc);
  }
  pe[(size_t)v*128 + n] = acc;
}

// partial mean/max pools over S-chunks
__global__ __launch_bounds__(128) void k_pool(const int* __restrict__ x, const float* __restrict__ emb,
      float* __restrict__ psum, float* __restrict__ pmax)
{
  const int b = blockIdx.x, c = blockIdx.y, e = threadIdx.x;
  const int* xb = x + (size_t)b*S + c*(S/16);
  float s=0.f, m=-INFINITY;
  for (int k=0;k<S/16;++k){
    int v = xb[k];
    float val = emb[(size_t)v*E + e];
    s += val; m = fmaxf(m,val);
  }
  psum[((size_t)b*16 + c)*E + e] = s;
  pmax[((size_t)b*16 + c)*E + e] = m;
}

// layer-0 recurrence, fused gather: pre[t] = pe[x[t]] (pe is 409 KB -> L2-hot).
// One wave per (d,b) chain; butterfly dot; pointer-increment addressing.
__global__ __attribute__((amdgpu_flat_work_group_size(64,64)))
__attribute__((amdgpu_waves_per_eu(1,1)))
void k_rec0(const int* __restrict__ x,
            const float* __restrict__ pe,
            ushort_t* __restrict__ y,
            const float* __restrict__ w_hh,
            float* __restrict__ hfin)
{
  const int c = blockIdx.x;           // 0..255
  const int d = c >> 7;
  const int b = c & 127;
  const int i = threadIdx.x;          // 0..63
  bool pick16=false, pick32=false;
  int cm[8];
  const int ba32 = (i^32)<<2, ba16 = (i^16)<<2;
  (void)ba32; (void)ba16;
  CALIB();
  f32x2 wp[32];
  LOAD_W8P(w_hh + (size_t)d*H*H);     // layer 0
  DECL_HD();
  const int* xb = x + (size_t)b*S;
  const char* peb = (const char*)(pe + d*H + i);   // + v*512B per row
  const int fwd = (d==0);
  const int dt = fwd ? 1 : -1;
  const int t0 = fwd ? 0 : S-1;
  ushort_t* yp = y + (size_t)b*S*(2*H) + d*H + i + (size_t)t0*(2*H);
  const int ystep = dt*(2*H);
  const int* xp = xb + t0 + 8*dt;     // x for t+8
  float h = 0.f;

#define ROWLD(vv) (*(const float*)(peb + (((unsigned)(vv))<<9)))
  int vx[8];                          // x values for t .. t+7 (slot = t&7)
  #pragma unroll
  for (int k=0;k<8;++k) vx[k] = xb[t0 + k*dt];
  float pl[4];                        // pe rows for t .. t+3 (slot = t&3)
  #pragma unroll
  for (int k=0;k<4;++k) pl[k] = ROWLD(vx[k]);

#define STEP0M(r) do {                                                       \
    float acc = pl[(r)&3];                                                   \
    pl[(r)&3] = ROWLD(vx[((r)+4)&7]);     /* row for t+4 */                  \
    vx[(r)&7] = *xp; xp += dt;            /* x for t+8  */                   \
    BSTEP(acc);                                                              \
    *yp = f2bf_fast(h); yp += ystep;                                         \
  } while(0)
#define STEP0T1(r) do {                                                      \
    float acc = pl[(r)&3];                                                   \
    pl[(r)&3] = ROWLD(vx[((r)+4)&7]);     /* row for t+4, still in range */  \
    BSTEP(acc);                                                              \
    *yp = f2bf_fast(h); yp += ystep;                                         \
  } while(0)
#define STEP0T2(r) do {                                                      \
    float acc = pl[(r)&3];                                                   \
    BSTEP(acc);                                                              \
    *yp = f2bf_fast(h); yp += ystep;                                         \
  } while(0)

  for (int tq=0; tq<S-8; tq+=8){      // 2040 main steps, no clamp anywhere
    STEP0M(0); STEP0M(1); STEP0M(2); STEP0M(3);
    STEP0M(4); STEP0M(5); STEP0M(6); STEP0M(7);
  }
  STEP0T1(0); STEP0T1(1); STEP0T1(2); STEP0T1(3);   // rows t+4 <= S-1
  STEP0T2(4); STEP0T2(5); STEP0T2(6); STEP0T2(7);   // ring-resident only
#undef STEP0M
#undef STEP0T1
#undef STEP0T2
#undef ROWLD
  hfin[((size_t)d*B + b)*H + i] = h;
}

// layers 1,2 recurrence: pre streamed from HBM (134 MB), depth-8 prefetch
// ring; butterfly dot; pointer-increment addressing; compile-time layer.
template<int LAYER, int WRITEY>
__global__ __attribute__((amdgpu_flat_work_group_size(64,64)))
__attribute__((amdgpu_waves_per_eu(1,1)))
void k_rec(const float* __restrict__ pre,
           ushort_t* __restrict__ y,
           const float* __restrict__ w_hh,
           float* __restrict__ hfin)
{
  const int c = blockIdx.x;           // 0..255
  const int d = c >> 7;
  const int b = c & 127;
  const int i = threadIdx.x;          // 0..63
  bool pick16=false, pick32=false;
  int cm[8];
  const int ba32 = (i^32)<<2, ba16 = (i^16)<<2;
  (void)ba32; (void)ba16;
  CALIB();
  f32x2 wp[32];
  LOAD_W8P(w_hh + (size_t)(LAYER*2+d)*H*H);
  DECL_HD();
  const float* pb = pre + ((size_t)d*M + (size_t)b*S)*H + i;
  const int fwd = (d==0);
  const int dt = fwd ? 1 : -1;
  const int t0 = fwd ? 0 : S-1;
  ushort_t* yp = y + (size_t)b*S*(2*H) + d*H + i + (size_t)t0*(2*H);
  const int ystep = dt*(2*H);
  const float* pf = pb + (size_t)(t0 + 8*dt)*H;  // prefetch ptr (t+8)
  const int pstep = dt*H;
  float h = 0.f;

  float pl[8];                        // pre values for t .. t+7 (slot = t&7)
  #pragma unroll
  for (int k=0;k<8;++k) pl[k] = pb[(size_t)(t0 + k*dt)*H];

#define STEPRM(r) do {                                                       \
    float acc = pl[r];                                                       \
    pl[r] = *pf; pf += pstep;             /* value for t+8 */                \
    BSTEP(acc);                                                              \
    if (WRITEY){ *yp = f2bf_fast(h); yp += ystep; }                          \
  } while(0)
#define STEPRT(r) do {                                                       \
    float acc = pl[r];                                                       \
    BSTEP(acc);                                                              \
    if (WRITEY){ *yp = f2bf_fast(h); yp += ystep; }                          \
  } while(0)

  for (int tq=0; tq<S-8; tq+=8){      // 2040 main steps, no clamp anywhere
    STEPRM(0); STEPRM(1); STEPRM(2); STEPRM(3);
    STEPRM(4); STEPRM(5); STEPRM(6); STEPRM(7);
  }
  STEPRT(0); STEPRT(1); STEPRT(2); STEPRT(3);       // ring-resident tail
  STEPRT(4); STEPRT(5); STEPRT(6); STEPRT(7);
#undef STEPRM
#undef STEPRT
  hfin[((size_t)d*B + b)*H + i] = h;
}

// layers 1,2 input projection: [M,128]@[128,128]^T. Yin is bf16, W is fp32.
#define KC 32
__global__ __launch_bounds__(256) void k_gemm(const ushort_t* __restrict__ Yin,
     const float* __restrict__ w_ih, const float* __restrict__ b_ih,
     const float* __restrict__ b_hh, float* __restrict__ pre, int layer)
{
  __shared__ float sY[KC][132];
  __shared__ float sW[KC][132];
  const int tid = threadIdx.x;
  const int m0 = blockIdx.x * 128;
  const int tn = (tid & 15) * 8;
  const int tm = (tid >> 4) * 8;
  float acc[8][8];
  #pragma unroll
  for (int a=0;a<8;++a)
    #pragma unroll
    for (int q=0;q<8;++q) acc[a][q]=0.f;
  const float* Wb = w_ih + (size_t)layer*2*H*E;
  for (int kc=0; kc<E; kc+=KC){
    #pragma unroll
    for (int r=0;r<2;++r){
      int idx = r*256 + tid;     // 0..511
      int ym = idx >> 2;         // 0..127
      int yk = (idx & 3)*8;      // 0,8,16,24
      const ushort_t* p = Yin + (size_t)(m0+ym)*E + kc + yk;
      ushort4 a = *(const ushort4*)p;
      ushort4 bq = *(const ushort4*)(p+4);
      sY[yk+0][ym]=bf2f(a.x);  sY[yk+1][ym]=bf2f(a.y);  sY[yk+2][ym]=bf2f(a.z);  sY[yk+3][ym]=bf2f(a.w);
      sY[yk+4][ym]=bf2f(bq.x); sY[yk+5][ym]=bf2f(bq.y); sY[yk+6][ym]=bf2f(bq.z); sY[yk+7][ym]=bf2f(bq.w);
    }
    #pragma unroll
    for (int r=0;r<4;++r){
      int idx = r*256 + tid;     // 0..1023
      int wn = idx >> 3;         // 0..127
      int wk = (idx & 7)*4;      // 0..28
      float4 v = *(const float4*)(Wb + (size_t)wn*E + kc + wk);
      sW[wk+0][wn]=v.x; sW[wk+1][wn]=v.y; sW[wk+2][wn]=v.z; sW[wk+3][wn]=v.w;
    }
    __syncthreads();
    #pragma unroll 4
    for (int k=0;k<KC;++k){
      float4 a0 = *(const float4*)&sY[k][tm];
      float4 a1 = *(const float4*)&sY[k][tm+4];
      float4 b0 = *(const float4*)&sW[k][tn];
      float4 b1 = *(const float4*)&sW[k][tn+4];
      float am[8]={a0.x,a0.y,a0.z,a0.w,a1.x,a1.y,a1.z,a1.w};
      float bn[8]={b0.x,b0.y,b0.z,b0.w,b1.x,b1.y,b1.z,b1.w};
      #pragma unroll
      for (int mi=0;mi<8;++mi)
        #pragma unroll
        for (int ni=0;ni<8;++ni)
          acc[mi][ni] = fmaf(am[mi], bn[ni], acc[mi][ni]);
    }
    __syncthreads();
  }
  const int d = tn >> 6;
  const int i0 = tn & 63;
  float bias[8];
  #pragma unroll
  for (int ni=0;ni<8;++ni)
    bias[ni] = b_ih[(size_t)(layer*2+d)*H + i0+ni] + b_hh[(size_t)(layer*2+d)*H + i0+ni];
  #pragma unroll
  for (int mi=0;mi<8;++mi){
    size_t off = ((size_t)d*M + (m0+tm+mi))*H + i0;
    float4 o0 = make_float4(acc[mi][0]+bias[0], acc[mi][1]+bias[1], acc[mi][2]+bias[2], acc[mi][3]+bias[3]);
    float4 o1 = make_float4(acc[mi][4]+bias[4], acc[mi][5]+bias[5], acc[mi][6]+bias[6], acc[mi][7]+bias[7]);
    *(float4*)(pre + off)     = o0;
    *(float4*)(pre + off + 4) = o1;
  }
}

// final FC head; also reduces the 16 pool partials. fp32 in/out.
__global__ __launch_bounds__(128) void k_fc(const float* __restrict__ psum, const float* __restrict__ pmax,
    const float* __restrict__ hfin, const float* __restrict__ fc1_w, const float* __restrict__ fc1_b,
    const float* __restrict__ fc2_w, const float* __restrict__ fc2_b, float* __restrict__ out)
{
  const int b = blockIdx.x, tid = threadIdx.x;
  __shared__ __align__(16) float comb[384];
  __shared__ float red[2];
  float s=0.f, m=-INFINITY;
  #pragma unroll
  for (int c=0;c<16;++c){
    s += psum[((size_t)b*16+c)*E + tid];
    m = fmaxf(m, pmax[((size_t)b*16+c)*E + tid]);
  }
  comb[128+tid] = s*(1.f/2048.f);
  comb[256+tid] = m;
  comb[tid] = (tid<64) ? hfin[(size_t)b*H + tid] : hfin[((size_t)B + b)*H + (tid-64)];
  __syncthreads();
  float acc = fc1_b[tid];
  const float4* wrow = (const float4*)(fc1_w + (size_t)tid*384);
  const float4* cb = (const float4*)comb;
  #pragma unroll 8
  for (int k=0;k<96;++k){
    float4 wv = wrow[k]; float4 cv = cb[k];
    acc = fmaf(wv.x,cv.x,acc); acc = fmaf(wv.y,cv.y,acc);
    acc = fmaf(wv.z,cv.z,acc); acc = fmaf(wv.w,cv.w,acc);
  }
  acc = fmaxf(acc, 0.f);
  float p = acc * fc2_w[tid];
  #pragma unroll
  for (int off=32; off>0; off>>=1) p += __shfl_down(p, off);
  if ((tid & 63)==0) red[tid>>6] = p;
  __syncthreads();
  if (tid==0) out[b] = red[0] + red[1] + fc2_b[0];
}

extern "C" void kernel_launch(void* const* d_in, const int* in_sizes, int n_in,
                              void* d_out, int out_size, void* d_ws, size_t ws_size,
                              hipStream_t stream)
{
  const int*   x     = (const int*)  d_in[0];
  const float* emb   = (const float*)d_in[1];
  const float* w_ih  = (const float*)d_in[2];
  const float* w_hh  = (const float*)d_in[3];
  const float* b_ih  = (const float*)d_in[4];
  const float* b_hh  = (const float*)d_in[5];
  const float* fc1_w = (const float*)d_in[6];
  const float* fc1_b = (const float*)d_in[7];
  const float* fc2_w = (const float*)d_in[8];
  const float* fc2_b = (const float*)d_in[9];
  float* out = (float*)d_out;

  // workspace: keep under ~204 MB
  char* ws = (char*)d_ws;
  float*    pre  = (float*)(ws);                                     // 2*M*H f32  = 134.2 MB (layers 1,2 only)
  ushort_t* y    = (ushort_t*)(ws + (size_t)2*M*H*4);                // M*128 bf16 =  67.1 MB
  float*    pe   = (float*)(ws + (size_t)2*M*H*4 + (size_t)M*128*2); // V*128 f32
  float*    psum = pe   + (size_t)V*128;                             // B*16*E f32
  float*    pmax = psum + (size_t)B*16*E;                            // B*16*E f32
  float*    hfin = pmax + (size_t)B*16*E;                            // 2*B*H f32

  k_pre_emb<<<V, 128, 0, stream>>>(emb, w_ih, b_ih, b_hh, pe);
  k_pool<<<dim3(B,16), 128, 0, stream>>>(x, emb, psum, pmax);
  k_rec0<<<256, 64, 0, stream>>>(x, pe, y, w_hh, hfin);
  k_gemm<<<M/128, 256, 0, stream>>>(y, w_ih, b_ih, b_hh, pre, 1);
  k_rec<1,1><<<256, 64, 0, stream>>>(pre, y, w_hh, hfin);
  k_gemm<<<M/128, 256, 0, stream>>>(y, w_ih, b_ih, b_hh, pre, 2);
  k_rec<2,0><<<256, 64, 0, stream>>>(pre, y, w_hh, hfin);
  k_fc<<<B, 128, 0, stream>>>(psum, pmax, hfin, fc1_w, fc1_b, fc2_w, fc2_b, out);
}

// Round 18
// 1273.242 us; speedup vs baseline: 1.0946x; 1.0403x over previous
//
#include <hip/hip_runtime.h>
#include <math.h>

#define B 128
#define S 2048
#define V 800
#define E 128
#define H 64
#define NL 3
#define M (B*S)

// C2 = 2*log2(e): exp2(C2*z) == exp(2z). Folded into pe/pre producers and W
// so the recurrence's exp2 argument needs no per-step multiply. State stays h.
#define C2 2.885390082f

typedef unsigned short ushort_t;
typedef float f32x2 __attribute__((ext_vector_type(2)));

__device__ __forceinline__ float bf2f(unsigned short u){
  return __uint_as_float(((unsigned int)u) << 16);
}
// single-instr bf16 round (RNE) for the y-store
__device__ __forceinline__ unsigned short f2bf_fast(float f){
  unsigned r;
  asm("v_cvt_pk_bf16_f32 %0, %1, %1" : "=v"(r) : "v"(f));
  return (unsigned short)r;
}
#if __has_builtin(__builtin_amdgcn_exp2f)
#define EXP2F(x) __builtin_amdgcn_exp2f(x)
#else
#define EXP2F(x) exp2f(x)
#endif
// tanh from a pre-scaled argument: accp = C2*z  ->  tanh(z)
__device__ __forceinline__ float tanh_scaled(float accp){
  float e = EXP2F(accp);
  return 1.f - 2.f*__builtin_amdgcn_rcpf(e+1.f);
}
// packed dual-f32 FMA, src1 LOW word broadcast to both halves via op_sel
// (R14-proven encoding)
__device__ __forceinline__ void pk_fma_b(f32x2& acc, f32x2 a, f32x2 b){
  asm("v_pk_fma_f32 %0, %1, %2, %0 op_sel:[0,0,0] op_sel_hi:[1,0,1]"
      : "+v"(acc) : "v"(a), "v"(b));
}
// packed dual-f32 MUL, same broadcast (encoding exonerated by R16/R17
// identical-failure bisection: it computed exactly zero-init+pk_fma's result)
__device__ __forceinline__ void pk_mul_b(f32x2& dst, f32x2 a, f32x2 b){
  asm("v_pk_mul_f32 %0, %1, %2 op_sel:[0,0] op_sel_hi:[1,0]"
      : "=v"(dst) : "v"(a), "v"(b));
}

// ---- all-VALU 8x8 butterfly matvec (R11/R13/R15-proven) -------------------
// Lane l owns h[l]. Rows per lane: l ^ G(k), G(k) = (k&3)|((k&4)<<2).
// Cols: preserve bits{0,1,4}; spread bits{2,3} (rot4 orbit) + bit5
// (permlane32 pair). Folds xor1/xor2 (quad_perm DPP) + xor16 (permlane16
// pair). Runtime calibration absorbs permlane pairing conventions.
// R18 = R15 + (a) C2 folded into producers/W (no per-step mul before exp2),
//             (b) pk_mul_b first-op for P1..P3 (no zero-init movs).
#define DPP_XOR1 0xB1    // quad_perm [1,0,3,2]
#define DPP_XOR2 0x4E    // quad_perm [2,3,0,1]
#define DPP_ROR4  0x124  // row_ror:4
#define DPP_ROR8  0x128  // row_ror:8
#define DPP_ROR12 0x12C  // row_ror:12
#define DPPI(v, ctrl) __builtin_amdgcn_update_dpp(0, (v), (ctrl), 0xf, 0xf, false)
#define DPPF(v, ctrl) __int_as_float(DPPI(__float_as_int(v), (ctrl)))
__device__ __forceinline__ float bperm(int addr, float v){
  return __int_as_float(__builtin_amdgcn_ds_bpermute(addr, __float_as_int(v)));
}
__device__ __host__ __forceinline__ constexpr int Gmask(int k){
  return (k & 3) | ((k & 4) << 2);      // {0,1,2,3,16,17,18,19}
}

#if __has_builtin(__builtin_amdgcn_permlane32_swap)
#define HAVE_PL32 1
#else
#define HAVE_PL32 0
#endif
#if __has_builtin(__builtin_amdgcn_permlane16_swap)
#define HAVE_PL16 1
#else
#define HAVE_PL16 0
#endif

#if HAVE_PL32
#define XOR32F(x) ({ auto r_ = __builtin_amdgcn_permlane32_swap(__float_as_uint(x), __float_as_uint(x), false, false); \
                     __uint_as_float(pick32 ? r_[0] : r_[1]); })
#else
#define XOR32F(x) bperm(ba32, (x))
#endif
#if HAVE_PL16
#define XOR16F(x) ({ auto r_ = __builtin_amdgcn_permlane16_swap(__float_as_uint(x), __float_as_uint(x), false, false); \
                     __uint_as_float(pick16 ? r_[0] : r_[1]); })
#else
#define XOR16F(x) bperm(ba16, (x))
#endif

// Calibration: fills pick16, pick32, cm[8] (true source lane of gather op j).
#define CALIB() do {                                                         \
  int mk_ = i;                                                               \
  int g32m_;                                                                 \
  if (HAVE_PL32) {                                                           \
    auto r_ = __builtin_amdgcn_permlane32_swap((unsigned)mk_, (unsigned)mk_, false, false); \
    pick32 = ((int)r_[0] == (mk_ ^ 32));                                     \
    g32m_ = pick32 ? (int)r_[0] : (int)r_[1];                                \
  } else {                                                                   \
    g32m_ = mk_ ^ 32;                                                        \
  }                                                                          \
  if (HAVE_PL16) {                                                           \
    auto r_ = __builtin_amdgcn_permlane16_swap((unsigned)mk_, (unsigned)mk_, false, false); \
    pick16 = ((int)r_[0] == (mk_ ^ 16));                                     \
  }                                                                          \
  cm[0]=mk_;   cm[1]=DPPI(mk_,DPP_ROR4);                                     \
  cm[2]=DPPI(mk_,DPP_ROR8);  cm[3]=DPPI(mk_,DPP_ROR12);                      \
  cm[4]=g32m_; cm[5]=DPPI(g32m_,DPP_ROR4);                                   \
  cm[6]=DPPI(g32m_,DPP_ROR8); cm[7]=DPPI(g32m_,DPP_ROR12);                   \
} while(0)

// W-tile load, scaled by C2: wp[q*8+j] = C2 * (W[i^G(2q)][cm j], W[i^G(2q+1)][cm j])
#define LOAD_W8P(wbase) do {                                                 \
  _Pragma("unroll")                                                          \
  for (int q=0;q<4;++q){                                                     \
    const float* r0_ = (wbase) + (size_t)(i ^ Gmask(2*q))*H;                 \
    const float* r1_ = (wbase) + (size_t)(i ^ Gmask(2*q+1))*H;               \
    _Pragma("unroll")                                                        \
    for (int j=0;j<8;++j)                                                    \
      wp[q*8+j] = (f32x2){ C2*r0_[cm[j]], C2*r1_[cm[j]] };                   \
  }                                                                          \
} while(0)

// persistent broadcast pairs (hi halves parked, never read via op_sel)
#define DECL_HD() f32x2 hd0={0,0},hd1={0,0},hd2={0,0},hd3={0,0},             \
                        hd4={0,0},hd5={0,0},hd6={0,0},hd7={0,0}

// one recurrence step: gather h, dot (P0 seeded with C2-scaled acc via
// pk_fma; P1..P3 start with pk_mul), unpack, fold, h = tanh_scaled(acc').
// acc_expr must be the C2-pre-scaled pre-activation.
#define BSTEP(acc_expr)                                                      \
  {                                                                          \
    hd0.x = h;                                                               \
    hd1.x = DPPF(h, DPP_ROR4);                                               \
    hd2.x = DPPF(h, DPP_ROR8);                                               \
    hd3.x = DPPF(h, DPP_ROR12);                                              \
    hd4.x = XOR32F(h);                                                       \
    hd5.x = DPPF(hd4.x, DPP_ROR4);                                           \
    hd6.x = DPPF(hd4.x, DPP_ROR8);                                           \
    hd7.x = DPPF(hd4.x, DPP_ROR12);                                          \
    f32x2 P0_ = {(acc_expr), 0.f};                                           \
    f32x2 P1_, P2_, P3_;                                                     \
    pk_fma_b(P0_,wp[0],hd0); pk_mul_b(P1_,wp[8],hd0);                        \
    pk_mul_b(P2_,wp[16],hd0); pk_mul_b(P3_,wp[24],hd0);                      \
    pk_fma_b(P0_,wp[1],hd1); pk_fma_b(P1_,wp[9],hd1);                        \
    pk_fma_b(P2_,wp[17],hd1); pk_fma_b(P3_,wp[25],hd1);                      \
    pk_fma_b(P0_,wp[2],hd2); pk_fma_b(P1_,wp[10],hd2);                       \
    pk_fma_b(P2_,wp[18],hd2); pk_fma_b(P3_,wp[26],hd2);                      \
    pk_fma_b(P0_,wp[3],hd3); pk_fma_b(P1_,wp[11],hd3);                       \
    pk_fma_b(P2_,wp[19],hd3); pk_fma_b(P3_,wp[27],hd3);                      \
    pk_fma_b(P0_,wp[4],hd4); pk_fma_b(P1_,wp[12],hd4);                       \
    pk_fma_b(P2_,wp[20],hd4); pk_fma_b(P3_,wp[28],hd4);                      \
    pk_fma_b(P0_,wp[5],hd5); pk_fma_b(P1_,wp[13],hd5);                       \
    pk_fma_b(P2_,wp[21],hd5); pk_fma_b(P3_,wp[29],hd5);                      \
    pk_fma_b(P0_,wp[6],hd6); pk_fma_b(P1_,wp[14],hd6);                       \
    pk_fma_b(P2_,wp[22],hd6); pk_fma_b(P3_,wp[30],hd6);                      \
    pk_fma_b(P0_,wp[7],hd7); pk_fma_b(P1_,wp[15],hd7);                       \
    pk_fma_b(P2_,wp[23],hd7); pk_fma_b(P3_,wp[31],hd7);                      \
    float p0_=P0_.x, p1_=P0_.y, p2_=P1_.x, p3_=P1_.y;                        \
    float p4_=P2_.x, p5_=P2_.y, p6_=P3_.x, p7_=P3_.y;                        \
    p0_ += DPPF(p1_, DPP_XOR1); p2_ += DPPF(p3_, DPP_XOR1);                  \
    p4_ += DPPF(p5_, DPP_XOR1); p6_ += DPPF(p7_, DPP_XOR1);                  \
    p0_ += DPPF(p2_, DPP_XOR2); p4_ += DPPF(p6_, DPP_XOR2);                  \
    p0_ += XOR16F(p4_);                                                      \
    h = tanh_scaled(p0_);                                                    \
  }
// ---------------------------------------------------------------------------

// pe[v][n] = C2 * (emb[v]·w_ih[0,n,:] + b_ih[0,n] + b_hh[0,n]),  n = d*64+i
__global__ __launch_bounds__(128) void k_pre_emb(const float* __restrict__ emb,
    const float* __restrict__ w_ih, const float* __restrict__ b_ih, const float* __restrict__ b_hh,
    float* __restrict__ pe)
{
  const int v = blockIdx.x;
  const int n = threadIdx.x;           // 0..127
  const float* er = emb + (size_t)v*E;
  const float* wr = w_ih + (size_t)n*E;   // layer 0 rows
  float acc = b_ih[n] + b_hh[n];
  #pragma unroll
  for (int e=0;e<E;e+=4){
    float4 ev = *(const float4*)(er+e);
    float4 wv = *(const float4*)(wr+e);
    acc = fmaf(ev.x, wv.x, acc);
    acc = fmaf(ev.y, wv.y, acc);
    acc = fmaf(ev.z, wv.z, acc);
    acc = fmaf(ev.w, wv.w, acc);
  }
  pe[(size_t)v*128 + n] = C2 * acc;
}

// partial mean/max pools over S-chunks
__global__ __launch_bounds__(128) void k_pool(const int* __restrict__ x, const float* __restrict__ emb,
      float* __restrict__ psum, float* __restrict__ pmax)
{
  const int b = blockIdx.x, c = blockIdx.y, e = threadIdx.x;
  const int* xb = x + (size_t)b*S + c*(S/16);
  float s=0.f, m=-INFINITY;
  for (int k=0;k<S/16;++k){
    int v = xb[k];
    float val = emb[(size_t)v*E + e];
    s += val; m = fmaxf(m,val);
  }
  psum[((size_t)b*16 + c)*E + e] = s;
  pmax[((size_t)b*16 + c)*E + e] = m;
}

// layer-0 recurrence, fused gather: pre'[t] = pe[x[t]] (pe L2-hot, C2-scaled).
__global__ __attribute__((amdgpu_flat_work_group_size(64,64)))
__attribute__((amdgpu_waves_per_eu(1,1)))
void k_rec0(const int* __restrict__ x,
            const float* __restrict__ pe,
            ushort_t* __restrict__ y,
            const float* __restrict__ w_hh,
            float* __restrict__ hfin)
{
  const int c = blockIdx.x;           // 0..255
  const int d = c >> 7;
  const int b = c & 127;
  const int i = threadIdx.x;          // 0..63
  bool pick16=false, pick32=false;
  int cm[8];
  const int ba32 = (i^32)<<2, ba16 = (i^16)<<2;
  (void)ba32; (void)ba16;
  CALIB();
  f32x2 wp[32];
  LOAD_W8P(w_hh + (size_t)d*H*H);     // layer 0
  DECL_HD();
  const int* xb = x + (size_t)b*S;
  const char* peb = (const char*)(pe + d*H + i);   // + v*512B per row
  const int fwd = (d==0);
  const int dt = fwd ? 1 : -1;
  const int t0 = fwd ? 0 : S-1;
  ushort_t* yp = y + (size_t)b*S*(2*H) + d*H + i + (size_t)t0*(2*H);
  const int ystep = dt*(2*H);
  const int* xp = xb + t0 + 8*dt;     // x for t+8
  float h = 0.f;

#define ROWLD(vv) (*(const float*)(peb + (((unsigned)(vv))<<9)))
  int vx[8];                          // x values for t .. t+7 (slot = t&7)
  #pragma unroll
  for (int k=0;k<8;++k) vx[k] = xb[t0 + k*dt];
  float pl[4];                        // pe rows for t .. t+3 (slot = t&3)
  #pragma unroll
  for (int k=0;k<4;++k) pl[k] = ROWLD(vx[k]);

#define STEP0M(q) do {                                                       \
    float acc = pl[(q)&3];                                                   \
    pl[(q)&3] = ROWLD(vx[((q)+4)&7]);     /* row for t+4 */                  \
    vx[(q)&7] = *xp; xp += dt;            /* x for t+8  */                   \
    BSTEP(acc);                                                              \
    *yp = f2bf_fast(h); yp += ystep;                                         \
  } while(0)
#define STEP0T1(q) do {                                                      \
    float acc = pl[(q)&3];                                                   \
    pl[(q)&3] = ROWLD(vx[((q)+4)&7]);     /* row for t+4, still in range */  \
    BSTEP(acc);                                                              \
    *yp = f2bf_fast(h); yp += ystep;                                         \
  } while(0)
#define STEP0T2(q) do {                                                      \
    float acc = pl[(q)&3];                                                   \
    BSTEP(acc);                                                              \
    *yp = f2bf_fast(h); yp += ystep;                                         \
  } while(0)

  for (int tq=0; tq<S-8; tq+=8){      // 2040 main steps, no clamp anywhere
    STEP0M(0); STEP0M(1); STEP0M(2); STEP0M(3);
    STEP0M(4); STEP0M(5); STEP0M(6); STEP0M(7);
  }
  STEP0T1(0); STEP0T1(1); STEP0T1(2); STEP0T1(3);   // rows t+4 <= S-1
  STEP0T2(4); STEP0T2(5); STEP0T2(6); STEP0T2(7);   // ring-resident only
#undef STEP0M
#undef STEP0T1
#undef STEP0T2
#undef ROWLD
  hfin[((size_t)d*B + b)*H + i] = h;
}

// layers 1,2 recurrence: pre' streamed from HBM (C2-scaled by k_gemm),
// depth-8 prefetch ring; pointer-increment addressing; compile-time layer.
template<int LAYER, int WRITEY>
__global__ __attribute__((amdgpu_flat_work_group_size(64,64)))
__attribute__((amdgpu_waves_per_eu(1,1)))
void k_rec(const float* __restrict__ pre,
           ushort_t* __restrict__ y,
           const float* __restrict__ w_hh,
           float* __restrict__ hfin)
{
  const int c = blockIdx.x;           // 0..255
  const int d = c >> 7;
  const int b = c & 127;
  const int i = threadIdx.x;          // 0..63
  bool pick16=false, pick32=false;
  int cm[8];
  const int ba32 = (i^32)<<2, ba16 = (i^16)<<2;
  (void)ba32; (void)ba16;
  CALIB();
  f32x2 wp[32];
  LOAD_W8P(w_hh + (size_t)(LAYER*2+d)*H*H);
  DECL_HD();
  const float* pb = pre + ((size_t)d*M + (size_t)b*S)*H + i;
  const int fwd = (d==0);
  const int dt = fwd ? 1 : -1;
  const int t0 = fwd ? 0 : S-1;
  ushort_t* yp = y + (size_t)b*S*(2*H) + d*H + i + (size_t)t0*(2*H);
  const int ystep = dt*(2*H);
  const float* pf = pb + (size_t)(t0 + 8*dt)*H;  // prefetch ptr (t+8)
  const int pstep = dt*H;
  float h = 0.f;

  float pl[8];                        // pre values for t .. t+7 (slot = t&7)
  #pragma unroll
  for (int k=0;k<8;++k) pl[k] = pb[(size_t)(t0 + k*dt)*H];

#define STEPRM(q) do {                                                       \
    float acc = pl[q];                                                       \
    pl[q] = *pf; pf += pstep;             /* value for t+8 */                \
    BSTEP(acc);                                                              \
    if (WRITEY){ *yp = f2bf_fast(h); yp += ystep; }                          \
  } while(0)
#define STEPRT(q) do {                                                       \
    float acc = pl[q];                                                       \
    BSTEP(acc);                                                              \
    if (WRITEY){ *yp = f2bf_fast(h); yp += ystep; }                          \
  } while(0)

  for (int tq=0; tq<S-8; tq+=8){      // 2040 main steps, no clamp anywhere
    STEPRM(0); STEPRM(1); STEPRM(2); STEPRM(3);
    STEPRM(4); STEPRM(5); STEPRM(6); STEPRM(7);
  }
  STEPRT(0); STEPRT(1); STEPRT(2); STEPRT(3);       // ring-resident tail
  STEPRT(4); STEPRT(5); STEPRT(6); STEPRT(7);
#undef STEPRM
#undef STEPRT
  hfin[((size_t)d*B + b)*H + i] = h;
}

// layers 1,2 input projection: [M,128]@[128,128]^T. Yin bf16, W fp32.
// Output pre-scaled by C2 for the mul-free exp2 in the recurrence.
#define KC 32
__global__ __launch_bounds__(256) void k_gemm(const ushort_t* __restrict__ Yin,
     const float* __restrict__ w_ih, const float* __restrict__ b_ih,
     const float* __restrict__ b_hh, float* __restrict__ pre, int layer)
{
  __shared__ float sY[KC][132];
  __shared__ float sW[KC][132];
  const int tid = threadIdx.x;
  const int m0 = blockIdx.x * 128;
  const int tn = (tid & 15) * 8;
  const int tm = (tid >> 4) * 8;
  float acc[8][8];
  #pragma unroll
  for (int a=0;a<8;++a)
    #pragma unroll
    for (int q=0;q<8;++q) acc[a][q]=0.f;
  const float* Wb = w_ih + (size_t)layer*2*H*E;
  for (int kc=0; kc<E; kc+=KC){
    #pragma unroll
    for (int r=0;r<2;++r){
      int idx = r*256 + tid;     // 0..511
      int ym = idx >> 2;         // 0..127
      int yk = (idx & 3)*8;      // 0,8,16,24
      const ushort_t* p = Yin + (size_t)(m0+ym)*E + kc + yk;
      ushort4 a = *(const ushort4*)p;
      ushort4 bq = *(const ushort4*)(p+4);
      sY[yk+0][ym]=bf2f(a.x);  sY[yk+1][ym]=bf2f(a.y);  sY[yk+2][ym]=bf2f(a.z);  sY[yk+3][ym]=bf2f(a.w);
      sY[yk+4][ym]=bf2f(bq.x); sY[yk+5][ym]=bf2f(bq.y); sY[yk+6][ym]=bf2f(bq.z); sY[yk+7][ym]=bf2f(bq.w);
    }
    #pragma unroll
    for (int r=0;r<4;++r){
      int idx = r*256 + tid;     // 0..1023
      int wn = idx >> 3;         // 0..127
      int wk = (idx & 7)*4;      // 0..28
      float4 v = *(const float4*)(Wb + (size_t)wn*E + kc + wk);
      sW[wk+0][wn]=v.x; sW[wk+1][wn]=v.y; sW[wk+2][wn]=v.z; sW[wk+3][wn]=v.w;
    }
    __syncthreads();
    #pragma unroll 4
    for (int k=0;k<KC;++k){
      float4 a0 = *(const float4*)&sY[k][tm];
      float4 a1 = *(const float4*)&sY[k][tm+4];
      float4 b0 = *(const float4*)&sW[k][tn];
      float4 b1 = *(const float4*)&sW[k][tn+4];
      float am[8]={a0.x,a0.y,a0.z,a0.w,a1.x,a1.y,a1.z,a1.w};
      float bn[8]={b0.x,b0.y,b0.z,b0.w,b1.x,b1.y,b1.z,b1.w};
      #pragma unroll
      for (int mi=0;mi<8;++mi)
        #pragma unroll
        for (int ni=0;ni<8;++ni)
          acc[mi][ni] = fmaf(am[mi], bn[ni], acc[mi][ni]);
    }
    __syncthreads();
  }
  const int d = tn >> 6;
  const int i0 = tn & 63;
  float bias[8];
  #pragma unroll
  for (int ni=0;ni<8;++ni)
    bias[ni] = b_ih[(size_t)(layer*2+d)*H + i0+ni] + b_hh[(size_t)(layer*2+d)*H + i0+ni];
  #pragma unroll
  for (int mi=0;mi<8;++mi){
    size_t off = ((size_t)d*M + (m0+tm+mi))*H + i0;
    float4 o0 = make_float4(C2*(acc[mi][0]+bias[0]), C2*(acc[mi][1]+bias[1]),
                            C2*(acc[mi][2]+bias[2]), C2*(acc[mi][3]+bias[3]));
    float4 o1 = make_float4(C2*(acc[mi][4]+bias[4]), C2*(acc[mi][5]+bias[5]),
                            C2*(acc[mi][6]+bias[6]), C2*(acc[mi][7]+bias[7]));
    *(float4*)(pre + off)     = o0;
    *(float4*)(pre + off + 4) = o1;
  }
}

// final FC head; also reduces the 16 pool partials. fp32 in/out.
__global__ __launch_bounds__(128) void k_fc(const float* __restrict__ psum, const float* __restrict__ pmax,
    const float* __restrict__ hfin, const float* __restrict__ fc1_w, const float* __restrict__ fc1_b,
    const float* __restrict__ fc2_w, const float* __restrict__ fc2_b, float* __restrict__ out)
{
  const int b = blockIdx.x, tid = threadIdx.x;
  __shared__ __align__(16) float comb[384];
  __shared__ float red[2];
  float s=0.f, m=-INFINITY;
  #pragma unroll
  for (int c=0;c<16;++c){
    s += psum[((size_t)b*16+c)*E + tid];
    m = fmaxf(m, pmax[((size_t)b*16+c)*E + tid]);
  }
  comb[128+tid] = s*(1.f/2048.f);
  comb[256+tid] = m;
  comb[tid] = (tid<64) ? hfin[(size_t)b*H + tid] : hfin[((size_t)B + b)*H + (tid-64)];
  __syncthreads();
  float acc = fc1_b[tid];
  const float4* wrow = (const float4*)(fc1_w + (size_t)tid*384);
  const float4* cb = (const float4*)comb;
  #pragma unroll 8
  for (int k=0;k<96;++k){
    float4 wv = wrow[k]; float4 cv = cb[k];
    acc = fmaf(wv.x,cv.x,acc); acc = fmaf(wv.y,cv.y,acc);
    acc = fmaf(wv.z,cv.z,acc); acc = fmaf(wv.w,cv.w,acc);
  }
  acc = fmaxf(acc, 0.f);
  float p = acc * fc2_w[tid];
  #pragma unroll
  for (int off=32; off>0; off>>=1) p += __shfl_down(p, off);
  if ((tid & 63)==0) red[tid>>6] = p;
  __syncthreads();
  if (tid==0) out[b] = red[0] + red[1] + fc2_b[0];
}

extern "C" void kernel_launch(void* const* d_in, const int* in_sizes, int n_in,
                              void* d_out, int out_size, void* d_ws, size_t ws_size,
                              hipStream_t stream)
{
  const int*   x     = (const int*)  d_in[0];
  const float* emb   = (const float*)d_in[1];
  const float* w_ih  = (const float*)d_in[2];
  const float* w_hh  = (const float*)d_in[3];
  const float* b_ih  = (const float*)d_in[4];
  const float* b_hh  = (const float*)d_in[5];
  const float* fc1_w = (const float*)d_in[6];
  const float* fc1_b = (const float*)d_in[7];
  const float* fc2_w = (const float*)d_in[8];
  const float* fc2_b = (const float*)d_in[9];
  float* out = (float*)d_out;

  // workspace: keep under ~204 MB
  char* ws = (char*)d_ws;
  float*    pre  = (float*)(ws);                                     // 2*M*H f32  = 134.2 MB (layers 1,2 only)
  ushort_t* y    = (ushort_t*)(ws + (size_t)2*M*H*4);                // M*128 bf16 =  67.1 MB
  float*    pe   = (float*)(ws + (size_t)2*M*H*4 + (size_t)M*128*2); // V*128 f32
  float*    psum = pe   + (size_t)V*128;                             // B*16*E f32
  float*    pmax = psum + (size_t)B*16*E;                            // B*16*E f32
  float*    hfin = pmax + (size_t)B*16*E;                            // 2*B*H f32

  k_pre_emb<<<V, 128, 0, stream>>>(emb, w_ih, b_ih, b_hh, pe);
  k_pool<<<dim3(B,16), 128, 0, stream>>>(x, emb, psum, pmax);
  k_rec0<<<256, 64, 0, stream>>>(x, pe, y, w_hh, hfin);
  k_gemm<<<M/128, 256, 0, stream>>>(y, w_ih, b_ih, b_hh, pre, 1);
  k_rec<1,1><<<256, 64, 0, stream>>>(pre, y, w_hh, hfin);
  k_gemm<<<M/128, 256, 0, stream>>>(y, w_ih, b_ih, b_hh, pre, 2);
  k_rec<2,0><<<256, 64, 0, stream>>>(pre, y, w_hh, hfin);
  k_fc<<<B, 128, 0, stream>>>(psum, pmax, hfin, fc1_w, fc1_b, fc2_w, fc2_b, out);
}